// Round 2
// baseline (436.557 us; speedup 1.0000x reference)
//
#include <hip/hip_runtime.h>

// MeshConv: out[e][o] = b[o] + sum_k combined[e][k] * W[o][k], K=160, OUT=64.
// R1: A-fragments built directly in registers (no c_lds, no per-tile barriers).
// Lane (col,quad) of wave w owns element e = tile*64 + w*16 + col, channel
// slice [quad*8, quad*8+8). The five descriptor segments of that slice are
// exactly the five K-step MFMA A-frags. W is pre-swizzled into LDS in frag
// order -> conflict-free ds_read_b128. Non-temporal output stores keep the
// 256 MB write stream from evicting x (128 MB, L3-resident) -> less over-fetch.

typedef __bf16 bf16_t;
typedef __bf16 bf16x8 __attribute__((ext_vector_type(8)));
typedef float  f32x4  __attribute__((ext_vector_type(4)));

#define EC      1000000
#define CCH     32
#define OUTD    64
#define KD      160          // 5*CCH
#define MT      64           // elements per tile
#define NTILES  (EC / MT)    // 15625 exactly
#define NFRAG   1280         // 5 ks * 4 tn * 4 quad * 16 col fragments of 8 bf16

__global__ __launch_bounds__(256)
void meshconv_kernel(const float* __restrict__ x,
                     const int*   __restrict__ nbr,
                     const float* __restrict__ W,
                     const float* __restrict__ bias,
                     float*       __restrict__ out)
{
    // W fragments, swizzled: frag index (((ks*4+tn)*4+quad)*16+col), 8 bf16 each.
    __shared__ bf16_t w_lds[NFRAG * 8];     // 20 KB

    const int tid  = threadIdx.x;
    const int wave = tid >> 6;
    const int lane = tid & 63;
    const int col  = lane & 15;
    const int quad = lane >> 4;

    // ---- one-time: W (64x160 f32, row-major) -> bf16 LDS, frag-swizzled ----
    for (int i = tid; i < NFRAG; i += 256) {
        const int fc  = i & 15;          // col
        const int fq  = (i >> 4) & 3;    // quad
        const int ftn = (i >> 6) & 3;    // tn
        const int fks = i >> 8;          // ks
        const float* src = W + (ftn * 16 + fc) * KD + fks * 32 + fq * 8;
        f32x4 w0 = *(const f32x4*)src;
        f32x4 w1 = *(const f32x4*)(src + 4);
        bf16x8 wf;
        wf[0]=(bf16_t)w0[0]; wf[1]=(bf16_t)w0[1]; wf[2]=(bf16_t)w0[2]; wf[3]=(bf16_t)w0[3];
        wf[4]=(bf16_t)w1[0]; wf[5]=(bf16_t)w1[1]; wf[6]=(bf16_t)w1[2]; wf[7]=(bf16_t)w1[3];
        *(bf16x8*)&w_lds[i * 8] = wf;
    }

    float bv[4];
#pragma unroll
    for (int tn = 0; tn < 4; ++tn) bv[tn] = bias[tn * 16 + col];

    __syncthreads();   // w_lds ready; read-only hereafter -> no more barriers

    for (int tile = blockIdx.x; tile < NTILES; tile += (int)gridDim.x) {
        const int e = tile * MT + wave * 16 + col;

        // ---- gather 5 rows' channel slice [quad*8, quad*8+8) ----
        const int4 nb = ((const int4*)nbr)[e];
        const float m0 = nb.x < 0 ? 0.f : 1.f;
        const float m1 = nb.y < 0 ? 0.f : 1.f;
        const float m2 = nb.z < 0 ? 0.f : 1.f;
        const float m3 = nb.w < 0 ? 0.f : 1.f;
        const int i0 = nb.x < 0 ? 0 : nb.x;
        const int i1 = nb.y < 0 ? 0 : nb.y;
        const int i2 = nb.z < 0 ? 0 : nb.z;
        const int i3 = nb.w < 0 ? 0 : nb.w;

        const int co = quad * 8;
        const f32x4* px  = (const f32x4*)(x + (size_t)e  * CCH + co);
        const f32x4* pa0 = (const f32x4*)(x + (size_t)i0 * CCH + co);
        const f32x4* pa1 = (const f32x4*)(x + (size_t)i1 * CCH + co);
        const f32x4* pb0 = (const f32x4*)(x + (size_t)i2 * CCH + co);
        const f32x4* pb1 = (const f32x4*)(x + (size_t)i3 * CCH + co);

        f32x4 xv[2], a0[2], a1[2], b0[2], b1[2];
#pragma unroll
        for (int h = 0; h < 2; ++h) {
            xv[h] = px[h];
            a0[h] = pa0[h] * m0;
            a1[h] = pa1[h] * m1;
            b0[h] = pb0[h] * m2;
            b1[h] = pb1[h] * m3;
        }

        // ---- descriptor slices == the 5 A-frags (ks = 0..4) ----
        bf16x8 af[5];
#pragma unroll
        for (int h = 0; h < 2; ++h) {
#pragma unroll
            for (int j = 0; j < 4; ++j) {
                const int jj = h * 4 + j;
                const float sa = a0[h][j] + a1[h][j];
                const float da = fabsf(a0[h][j] - a1[h][j]);
                const float sb = b0[h][j] + b1[h][j];
                const float db = fabsf(b0[h][j] - b1[h][j]);
                af[0][jj] = (bf16_t)xv[h][j];
                af[1][jj] = (bf16_t)(sa + sb);
                af[2][jj] = (bf16_t)(da + db);
                af[3][jj] = (bf16_t)fabsf(sa - sb);
                af[4][jj] = (bf16_t)fabsf(da - db);
            }
        }

        // ---- MFMA: 16 rows x 64 cols per wave, K = 5 x 32 ----
        f32x4 acc[4] = {{0.f,0.f,0.f,0.f},{0.f,0.f,0.f,0.f},
                        {0.f,0.f,0.f,0.f},{0.f,0.f,0.f,0.f}};
#pragma unroll
        for (int ks = 0; ks < 5; ++ks) {
#pragma unroll
            for (int tn = 0; tn < 4; ++tn) {
                const bf16x8 bfr = *(const bf16x8*)&w_lds[(((ks*4+tn)*4+quad)*16 + col) * 8];
                acc[tn] = __builtin_amdgcn_mfma_f32_16x16x32_bf16(af[ks], bfr, acc[tn], 0, 0, 0);
            }
        }

        // ---- epilogue: C/D layout col=lane&15, row=quad*4+reg; nt stores ----
#pragma unroll
        for (int tn = 0; tn < 4; ++tn) {
            float* op = out + (size_t)(tile * MT + wave * 16 + quad * 4) * OUTD + tn * 16 + col;
#pragma unroll
            for (int r = 0; r < 4; ++r)
                __builtin_nontemporal_store(acc[tn][r] + bv[tn], op + (size_t)r * OUTD);
        }
    }
}

extern "C" void kernel_launch(void* const* d_in, const int* in_sizes, int n_in,
                              void* d_out, int out_size, void* d_ws, size_t ws_size,
                              hipStream_t stream) {
    const float* x    = (const float*)d_in[0];
    const int*   nbr  = (const int*)d_in[1];
    const float* W    = (const float*)d_in[2];
    const float* bias = (const float*)d_in[3];
    float* out = (float*)d_out;
    // grid-stride over 15625 tiles; 3072 blocks (~5 tiles each) keeps good
    // balance whatever the resident-blocks/CU count turns out to be.
    meshconv_kernel<<<dim3(3072), dim3(256), 0, stream>>>(x, nbr, W, bias, out);
}

// Round 3
// 413.766 us; speedup vs baseline: 1.0551x; 1.0551x over previous
//
#include <hip/hip_runtime.h>

// MeshConv: out[e][o] = b[o] + sum_k combined[e][k] * W[o][k], K=160, OUT=64.
// R2: (a) epilogue transposes acc through per-wave LDS so output stores are
// full-line (1KB/instr) non-temporal dwordx4 -> write stream bypasses L3
// cleanly and stops evicting x (128 MB, L3-resident); (b) software prefetch
// of next tile's 10 gather f32x4 loads hides gather latency behind MFMA.

typedef __bf16 bf16_t;
typedef __bf16 bf16x8 __attribute__((ext_vector_type(8)));
typedef float  f32x4  __attribute__((ext_vector_type(4)));

#define EC      1000000
#define CCH     32
#define OUTD    64
#define KD      160          // 5*CCH
#define MT      64           // elements per tile
#define NTILES  (EC / MT)    // 15625
#define NFRAG   1280         // 5 ks * 4 tn * 4 quad * 16 col frags of 8 bf16
#define TSTR    68           // epilogue LDS row stride (floats): 16B-aligned rows, 2-way max
#define GRID    1024

__global__ __launch_bounds__(256)
void meshconv_kernel(const float* __restrict__ x,
                     const int*   __restrict__ nbr,
                     const float* __restrict__ W,
                     const float* __restrict__ bias,
                     float*       __restrict__ out)
{
    __shared__ bf16_t w_lds[NFRAG * 8];                         // 20.0 KB
    __shared__ __attribute__((aligned(16))) float t_lds[4 * 16 * TSTR]; // 17.0 KB

    const int tid  = threadIdx.x;
    const int wave = tid >> 6;
    const int lane = tid & 63;
    const int col  = lane & 15;
    const int quad = lane >> 4;

    // ---- one-time: W (64x160 f32) -> bf16 LDS, frag-swizzled ----
    for (int i = tid; i < NFRAG; i += 256) {
        const int fc  = i & 15;
        const int fq  = (i >> 4) & 3;
        const int ftn = (i >> 6) & 3;
        const int fks = i >> 8;
        const float* src = W + (ftn * 16 + fc) * KD + fks * 32 + fq * 8;
        f32x4 w0 = *(const f32x4*)src;
        f32x4 w1 = *(const f32x4*)(src + 4);
        bf16x8 wf;
        wf[0]=(bf16_t)w0[0]; wf[1]=(bf16_t)w0[1]; wf[2]=(bf16_t)w0[2]; wf[3]=(bf16_t)w0[3];
        wf[4]=(bf16_t)w1[0]; wf[5]=(bf16_t)w1[1]; wf[6]=(bf16_t)w1[2]; wf[7]=(bf16_t)w1[3];
        *(bf16x8*)&w_lds[i * 8] = wf;
    }

    float bv[4];
#pragma unroll
    for (int tn = 0; tn < 4; ++tn) bv[tn] = bias[tn * 16 + col];

    float* tw = &t_lds[wave * 16 * TSTR];   // per-wave region, no cross-wave sharing

    __syncthreads();   // w_lds ready; read-only hereafter

    // Gather one tile's 5 rows (channel slice [quad*8, quad*8+8)) raw.
    auto load_tile = [&](int t, int4& nb, f32x4* buf) {
        const int e = t * MT + wave * 16 + col;
        nb = ((const int4*)nbr)[e];
        const int i0 = nb.x < 0 ? 0 : nb.x;
        const int i1 = nb.y < 0 ? 0 : nb.y;
        const int i2 = nb.z < 0 ? 0 : nb.z;
        const int i3 = nb.w < 0 ? 0 : nb.w;
        const int co = quad * 8;
        const f32x4* p;
        p = (const f32x4*)(x + (size_t)e  * CCH + co); buf[0] = p[0]; buf[1] = p[1];
        p = (const f32x4*)(x + (size_t)i0 * CCH + co); buf[2] = p[0]; buf[3] = p[1];
        p = (const f32x4*)(x + (size_t)i1 * CCH + co); buf[4] = p[0]; buf[5] = p[1];
        p = (const f32x4*)(x + (size_t)i2 * CCH + co); buf[6] = p[0]; buf[7] = p[1];
        p = (const f32x4*)(x + (size_t)i3 * CCH + co); buf[8] = p[0]; buf[9] = p[1];
    };

    int tile = blockIdx.x;
    int4  nbc;
    f32x4 cb[10];
    if (tile < NTILES) load_tile(tile, nbc, cb);

    for (; tile < NTILES; tile += GRID) {
        // ---- prefetch next tile (stays in flight through MFMA + epilogue) ----
        const int nxt = tile + GRID;
        int4  nbn;
        f32x4 pb[10];
        if (nxt < NTILES) load_tile(nxt, nbn, pb);

        // ---- descriptor slices == the 5 A-frags ----
        const float m0 = nbc.x < 0 ? 0.f : 1.f;
        const float m1 = nbc.y < 0 ? 0.f : 1.f;
        const float m2 = nbc.z < 0 ? 0.f : 1.f;
        const float m3 = nbc.w < 0 ? 0.f : 1.f;

        bf16x8 af[5];
#pragma unroll
        for (int h = 0; h < 2; ++h) {
#pragma unroll
            for (int j = 0; j < 4; ++j) {
                const int jj = h * 4 + j;
                const float va0 = cb[2 + h][j] * m0;
                const float va1 = cb[4 + h][j] * m1;
                const float vb0 = cb[6 + h][j] * m2;
                const float vb1 = cb[8 + h][j] * m3;
                const float sa = va0 + va1;
                const float da = fabsf(va0 - va1);
                const float sb = vb0 + vb1;
                const float db = fabsf(vb0 - vb1);
                af[0][jj] = (bf16_t)cb[h][j];
                af[1][jj] = (bf16_t)(sa + sb);
                af[2][jj] = (bf16_t)(da + db);
                af[3][jj] = (bf16_t)fabsf(sa - sb);
                af[4][jj] = (bf16_t)fabsf(da - db);
            }
        }

        // ---- MFMA: 16 rows x 64 cols per wave, K = 5 x 32 ----
        f32x4 acc[4] = {{0.f,0.f,0.f,0.f},{0.f,0.f,0.f,0.f},
                        {0.f,0.f,0.f,0.f},{0.f,0.f,0.f,0.f}};
#pragma unroll
        for (int ks = 0; ks < 5; ++ks) {
#pragma unroll
            for (int tn = 0; tn < 4; ++tn) {
                const bf16x8 bfr = *(const bf16x8*)&w_lds[(((ks*4+tn)*4+quad)*16 + col) * 8];
                acc[tn] = __builtin_amdgcn_mfma_f32_16x16x32_bf16(af[ks], bfr, acc[tn], 0, 0, 0);
            }
        }

        // ---- epilogue: in-wave LDS transpose -> full-line nt dwordx4 stores ----
        // acc[tn][r] = C(row=quad*4+r, col=tn*16+col)
#pragma unroll
        for (int tn = 0; tn < 4; ++tn)
#pragma unroll
            for (int r = 0; r < 4; ++r)
                tw[(quad * 4 + r) * TSTR + tn * 16 + col] = acc[tn][r] + bv[tn];

#pragma unroll
        for (int r = 0; r < 4; ++r) {
            const f32x4 v = *(const f32x4*)&tw[(quad * 4 + r) * TSTR + col * 4];
            float* op = out + (size_t)(tile * MT + wave * 16 + quad * 4 + r) * OUTD + col * 4;
            __builtin_nontemporal_store(v, (f32x4*)op);
        }

        // ---- rotate prefetch buffer ----
        nbc = nbn;
#pragma unroll
        for (int k = 0; k < 10; ++k) cb[k] = pb[k];
    }
}

extern "C" void kernel_launch(void* const* d_in, const int* in_sizes, int n_in,
                              void* d_out, int out_size, void* d_ws, size_t ws_size,
                              hipStream_t stream) {
    const float* x    = (const float*)d_in[0];
    const int*   nbr  = (const int*)d_in[1];
    const float* W    = (const float*)d_in[2];
    const float* bias = (const float*)d_in[3];
    float* out = (float*)d_out;
    // 1024 blocks (grid-stride, ~15 tiles each): enough blocks for any
    // residency, long-lived blocks make the prefetch pipeline effective.
    meshconv_kernel<<<dim3(GRID), dim3(256), 0, stream>>>(x, nbr, W, bias, out);
}